// Round 6
// baseline (254.081 us; speedup 1.0000x reference)
//
#include <hip/hip_runtime.h>

// Inputs and outputs are float32 (established R1/R3).
#define NCLS 91
#define W1_LD 2052   // repn_w1 row length (2C+4)

// ---------- K1: p_part[z][i][r] = feats[i, z*256:+256] . Wcomb[r, z*256:+256] ----------
// Wcomb rows 0..255 = wf1, 256..511 = wf2. grid (8 r, 16 i, 4 z), 128 thr.
// Tile 32i x 64r, BK=64 (4 kt iters), 4x4 micro, reg-prefetch.
__global__ __launch_bounds__(128) void k_p12(const float* __restrict__ feats,
                                             const float* __restrict__ w1f,
                                             float* __restrict__ pp) {
    int r0 = blockIdx.x * 64, i0 = blockIdx.y * 32, z = blockIdx.z;
    int tid = threadIdx.x, tx = tid & 15, ty = tid >> 4;
    __shared__ float As[64 * 32];   // [k][i]
    __shared__ float Bs[64 * 64];   // [k][r]
    float* pout = pp + z * 262144;
    int ai = tid & 31, akq = (tid >> 5) * 16;
    int br = tid & 63, bkq = (tid >> 6) * 32;
    const float* abase = feats + (i0 + ai) * 1024 + z * 256 + akq;
    int rg = r0 + br;
    const float* bbase = w1f + (rg < 256 ? rg * W1_LD : (rg - 256) * W1_LD + 1024)
                       + z * 256 + bkq;
    float4 av[4], bv[8];
#pragma unroll
    for (int s = 0; s < 4; ++s) av[s] = *(const float4*)(abase + 4 * s);
#pragma unroll
    for (int s = 0; s < 8; ++s) bv[s] = *(const float4*)(bbase + 4 * s);
    float acc[4][4] = {};
    for (int kt = 0; kt < 4; ++kt) {
#pragma unroll
        for (int s = 0; s < 4; ++s) {
            int k = akq + 4 * s;
            As[(k + 0) * 32 + ai] = av[s].x; As[(k + 1) * 32 + ai] = av[s].y;
            As[(k + 2) * 32 + ai] = av[s].z; As[(k + 3) * 32 + ai] = av[s].w;
        }
#pragma unroll
        for (int s = 0; s < 8; ++s) {
            int k = bkq + 4 * s;
            Bs[(k + 0) * 64 + br] = bv[s].x; Bs[(k + 1) * 64 + br] = bv[s].y;
            Bs[(k + 2) * 64 + br] = bv[s].z; Bs[(k + 3) * 64 + br] = bv[s].w;
        }
        __syncthreads();
        if (kt + 1 < 4) {
#pragma unroll
            for (int s = 0; s < 4; ++s) av[s] = *(const float4*)(abase + (kt + 1) * 64 + 4 * s);
#pragma unroll
            for (int s = 0; s < 8; ++s) bv[s] = *(const float4*)(bbase + (kt + 1) * 64 + 4 * s);
        }
#pragma unroll
        for (int k = 0; k < 64; ++k) {
            float4 a4 = *(const float4*)(As + k * 32 + ty * 4);
            float4 b4 = *(const float4*)(Bs + k * 64 + tx * 4);
            acc[0][0] = fmaf(a4.x, b4.x, acc[0][0]); acc[0][1] = fmaf(a4.x, b4.y, acc[0][1]);
            acc[0][2] = fmaf(a4.x, b4.z, acc[0][2]); acc[0][3] = fmaf(a4.x, b4.w, acc[0][3]);
            acc[1][0] = fmaf(a4.y, b4.x, acc[1][0]); acc[1][1] = fmaf(a4.y, b4.y, acc[1][1]);
            acc[1][2] = fmaf(a4.y, b4.z, acc[1][2]); acc[1][3] = fmaf(a4.y, b4.w, acc[1][3]);
            acc[2][0] = fmaf(a4.z, b4.x, acc[2][0]); acc[2][1] = fmaf(a4.z, b4.y, acc[2][1]);
            acc[2][2] = fmaf(a4.z, b4.z, acc[2][2]); acc[2][3] = fmaf(a4.z, b4.w, acc[2][3]);
            acc[3][0] = fmaf(a4.w, b4.x, acc[3][0]); acc[3][1] = fmaf(a4.w, b4.y, acc[3][1]);
            acc[3][2] = fmaf(a4.w, b4.z, acc[3][2]); acc[3][3] = fmaf(a4.w, b4.w, acc[3][3]);
        }
        __syncthreads();
    }
#pragma unroll
    for (int ii = 0; ii < 4; ++ii)
        *(float4*)(pout + (i0 + ty * 4 + ii) * 512 + r0 + tx * 4) =
            make_float4(acc[ii][0], acc[ii][1], acc[ii][2], acc[ii][3]);
}

// ---------- K2: rel[i][j], summing the four K-partials during staging ----------
__global__ __launch_bounds__(256) void k_rel(const float* __restrict__ pp,
                                             const float* __restrict__ w1f,
                                             const float* __restrict__ b1f,
                                             const float* __restrict__ w2f,
                                             const float* __restrict__ b2f,
                                             const float* __restrict__ boxesf,
                                             float* __restrict__ rel_out) {
    int j0 = blockIdx.x * 64, i0 = blockIdx.y * 16;
    int tid = threadIdx.x, tx = tid & 63, ty = tid >> 6;
    const float* pp0 = pp;
    const float* pp1 = pp + 262144;
    const float* pp2 = pp + 524288;
    const float* pp3 = pp + 786432;
    __shared__ float As1[32 * 17];
    __shared__ float Bs[32 * 64];
    __shared__ float Awg[32 * 4];
    __shared__ float Aw2[32];
    float4 bj = *(const float4*)(boxesf + (j0 + tx) * 4);
    float g[4][4];
#pragma unroll
    for (int s = 0; s < 4; ++s) {
        float4 bi = *(const float4*)(boxesf + (i0 + ty * 4 + s) * 4);
        g[s][0] = fabsf(bi.x - bj.x); g[s][1] = fabsf(bi.y - bj.y);
        g[s][2] = fabsf(bi.z - bj.z); g[s][3] = fabsf(bi.w - bj.w);
    }
    float acc[4] = {0.f, 0.f, 0.f, 0.f};
    int ali = tid & 15, alh = (tid >> 4) * 4;
    int blj = tid & 63, blh = (tid >> 6) * 8;
    for (int ch = 0; ch < 8; ++ch) {
        int hb = ch * 32;
        if (tid < 128) {
            int off = (i0 + ali) * 512 + hb + alh;
            float4 v0 = *(const float4*)(pp0 + off);
            float4 v1 = *(const float4*)(pp1 + off);
            float4 v2 = *(const float4*)(pp2 + off);
            float4 v3 = *(const float4*)(pp3 + off);
            float4 b  = *(const float4*)(b1f + hb + alh);
            As1[(alh + 0) * 17 + ali] = (v0.x + v1.x) + (v2.x + v3.x) + b.x;
            As1[(alh + 1) * 17 + ali] = (v0.y + v1.y) + (v2.y + v3.y) + b.y;
            As1[(alh + 2) * 17 + ali] = (v0.z + v1.z) + (v2.z + v3.z) + b.z;
            As1[(alh + 3) * 17 + ali] = (v0.w + v1.w) + (v2.w + v3.w) + b.w;
        }
#pragma unroll
        for (int s = 0; s < 2; ++s) {
            int h = blh + 4 * s;
            int off = (j0 + blj) * 512 + 256 + hb + h;
            float4 u0 = *(const float4*)(pp0 + off);
            float4 u1 = *(const float4*)(pp1 + off);
            float4 u2 = *(const float4*)(pp2 + off);
            float4 u3 = *(const float4*)(pp3 + off);
            Bs[(h + 0) * 64 + blj] = (u0.x + u1.x) + (u2.x + u3.x);
            Bs[(h + 1) * 64 + blj] = (u0.y + u1.y) + (u2.y + u3.y);
            Bs[(h + 2) * 64 + blj] = (u0.z + u1.z) + (u2.z + u3.z);
            Bs[(h + 3) * 64 + blj] = (u0.w + u1.w) + (u2.w + u3.w);
        }
        if (tid < 32) {
            int hg = hb + tid;
            *(float4*)(Awg + tid * 4) = *(const float4*)(w1f + hg * W1_LD + 2048);
            Aw2[tid] = w2f[hg];
        }
        __syncthreads();
#pragma unroll
        for (int hh = 0; hh < 32; ++hh) {
            float4 wg = *(const float4*)(Awg + hh * 4);
            float w2v = Aw2[hh];
            float p2v = Bs[hh * 64 + tx];
            float s0 = As1[hh * 17 + ty * 4 + 0];
            float s1 = As1[hh * 17 + ty * 4 + 1];
            float s2 = As1[hh * 17 + ty * 4 + 2];
            float s3 = As1[hh * 17 + ty * 4 + 3];
            float t0 = s0 + p2v;
            t0 = fmaf(g[0][0], wg.x, t0); t0 = fmaf(g[0][1], wg.y, t0);
            t0 = fmaf(g[0][2], wg.z, t0); t0 = fmaf(g[0][3], wg.w, t0);
            acc[0] = fmaf(w2v, fmaxf(t0, 0.f), acc[0]);
            float t1 = s1 + p2v;
            t1 = fmaf(g[1][0], wg.x, t1); t1 = fmaf(g[1][1], wg.y, t1);
            t1 = fmaf(g[1][2], wg.z, t1); t1 = fmaf(g[1][3], wg.w, t1);
            acc[1] = fmaf(w2v, fmaxf(t1, 0.f), acc[1]);
            float t2 = s2 + p2v;
            t2 = fmaf(g[2][0], wg.x, t2); t2 = fmaf(g[2][1], wg.y, t2);
            t2 = fmaf(g[2][2], wg.z, t2); t2 = fmaf(g[2][3], wg.w, t2);
            acc[2] = fmaf(w2v, fmaxf(t2, 0.f), acc[2]);
            float t3 = s3 + p2v;
            t3 = fmaf(g[3][0], wg.x, t3); t3 = fmaf(g[3][1], wg.y, t3);
            t3 = fmaf(g[3][2], wg.z, t3); t3 = fmaf(g[3][3], wg.w, t3);
            acc[3] = fmaf(w2v, fmaxf(t3, 0.f), acc[3]);
        }
        __syncthreads();
    }
    float b2v = b2f[0];
#pragma unroll
    for (int s = 0; s < 4; ++s)
        rel_out[(i0 + ty * 4 + s) * 512 + j0 + tx] = acc[s] + b2v;
}

// ---------- K3: per-row top-(k+1), drop first; count in-degrees ----------
__global__ void k_topk(const float* __restrict__ relf, const int* __restrict__ kp,
                       int* __restrict__ nbrs, int* __restrict__ count) {
    int i = blockIdx.x, lane = threadIdx.x;
    int k = *kp;
    float v[8]; int ids[8];
    for (int q = 0; q < 8; ++q) {
        int j = lane + 64 * q;
        v[q] = relf[i * 512 + j];
        ids[q] = j;
    }
    for (int pick = 0; pick < k + 1; ++pick) {
        float bv = -INFINITY; int bidx = 1 << 30;
        for (int q = 0; q < 8; ++q)
            if (v[q] > bv || (v[q] == bv && ids[q] < bidx)) { bv = v[q]; bidx = ids[q]; }
        for (int off = 32; off > 0; off >>= 1) {
            float ov = __shfl_down(bv, off);
            int oi = __shfl_down(bidx, off);
            if (ov > bv || (ov == bv && oi < bidx)) { bv = ov; bidx = oi; }
        }
        bv = __shfl(bv, 0); bidx = __shfl(bidx, 0);
        if (pick >= 1 && lane == 0) {
            nbrs[i * 8 + (pick - 1)] = bidx;
            atomicAdd(&count[bidx], 1);
        }
        for (int q = 0; q < 8; ++q) if (ids[q] == bidx) v[q] = -INFINITY;
    }
    if (lane == 0) atomicAdd(&count[i], 1);
}

// ---------- K4: exclusive scan ----------
__global__ void k_scan(const int* __restrict__ count, int* __restrict__ offs) {
    __shared__ int s[512];
    int t = threadIdx.x;
    s[t] = count[t];
    __syncthreads();
    for (int off = 1; off < 512; off <<= 1) {
        int v = (t >= off) ? s[t - off] : 0;
        __syncthreads();
        s[t] += v;
        __syncthreads();
    }
    offs[t + 1] = s[t];
    if (t == 0) offs[0] = 0;
}

// ---------- K5: fill in-edge lists ----------
__global__ void k_fill(const int* __restrict__ nbrs, const int* __restrict__ kp,
                       const int* __restrict__ offs, int* __restrict__ cursor,
                       int* __restrict__ inlist) {
    int i = blockIdx.x * blockDim.x + threadIdx.x;
    if (i >= 512) return;
    int k = *kp;
    for (int q = 0; q < k; ++q) {
        int d = nbrs[i * 8 + q] & 511;
        int pos = atomicAdd(&cursor[d], 1);
        inlist[offs[d] + pos] = i;
    }
    int pos = atomicAdd(&cursor[i], 1);
    inlist[offs[i] + pos] = i;
}

// ---------- K6: GAT1 GEMM, K-split x4, atomic accumulate into zeroed hX ----------
// grid (16 n, 16 i, 4 kz), 128 thr. Tile 32i x 64n, kz chunk = 256 K-rows.
__global__ __launch_bounds__(128) void k_gat1(const float* __restrict__ feats,
                                              const float* __restrict__ Wg,
                                              float* __restrict__ hX) {
    int n0 = blockIdx.x * 64, i0 = blockIdx.y * 32, kz = blockIdx.z;
    int tid = threadIdx.x, tx = tid & 15, ty = tid >> 4;
    __shared__ float As[64 * 32];   // [k][i]
    __shared__ float Bs[64 * 68];   // [k][n] pad 68
    int ai = tid & 31, akq = (tid >> 5) * 16;
    int bn4 = (tid & 15) * 4, bkl = tid >> 4;
    const float* abase = feats + (i0 + ai) * 1024 + kz * 256 + akq;
    const float* bbase = Wg + (kz * 256 + bkl) * 1024 + n0 + bn4;
    float4 av[4], bv[8];
#pragma unroll
    for (int s = 0; s < 4; ++s) av[s] = *(const float4*)(abase + 4 * s);
#pragma unroll
    for (int s = 0; s < 8; ++s) bv[s] = *(const float4*)(bbase + (8 * s) * 1024);
    float acc[4][4] = {};
    for (int kt = 0; kt < 4; ++kt) {
#pragma unroll
        for (int s = 0; s < 4; ++s) {
            int k = akq + 4 * s;
            As[(k + 0) * 32 + ai] = av[s].x; As[(k + 1) * 32 + ai] = av[s].y;
            As[(k + 2) * 32 + ai] = av[s].z; As[(k + 3) * 32 + ai] = av[s].w;
        }
#pragma unroll
        for (int s = 0; s < 8; ++s)
            *(float4*)(Bs + (bkl + 8 * s) * 68 + bn4) = bv[s];
        __syncthreads();
        if (kt + 1 < 4) {
#pragma unroll
            for (int s = 0; s < 4; ++s)
                av[s] = *(const float4*)(abase + (kt + 1) * 64 + 4 * s);
#pragma unroll
            for (int s = 0; s < 8; ++s)
                bv[s] = *(const float4*)(bbase + ((kt + 1) * 64 + 8 * s) * 1024);
        }
#pragma unroll
        for (int k = 0; k < 64; ++k) {
            float4 a4 = *(const float4*)(As + k * 32 + ty * 4);
            float4 b4 = *(const float4*)(Bs + k * 68 + tx * 4);
            acc[0][0] = fmaf(a4.x, b4.x, acc[0][0]); acc[0][1] = fmaf(a4.x, b4.y, acc[0][1]);
            acc[0][2] = fmaf(a4.x, b4.z, acc[0][2]); acc[0][3] = fmaf(a4.x, b4.w, acc[0][3]);
            acc[1][0] = fmaf(a4.y, b4.x, acc[1][0]); acc[1][1] = fmaf(a4.y, b4.y, acc[1][1]);
            acc[1][2] = fmaf(a4.y, b4.z, acc[1][2]); acc[1][3] = fmaf(a4.y, b4.w, acc[1][3]);
            acc[2][0] = fmaf(a4.z, b4.x, acc[2][0]); acc[2][1] = fmaf(a4.z, b4.y, acc[2][1]);
            acc[2][2] = fmaf(a4.z, b4.z, acc[2][2]); acc[2][3] = fmaf(a4.z, b4.w, acc[2][3]);
            acc[3][0] = fmaf(a4.w, b4.x, acc[3][0]); acc[3][1] = fmaf(a4.w, b4.y, acc[3][1]);
            acc[3][2] = fmaf(a4.w, b4.z, acc[3][2]); acc[3][3] = fmaf(a4.w, b4.w, acc[3][3]);
        }
        __syncthreads();
    }
#pragma unroll
    for (int ii = 0; ii < 4; ++ii) {
        float* hp = hX + (i0 + ty * 4 + ii) * 1024 + n0 + tx * 4;
        atomicAdd(hp + 0, acc[ii][0]);
        atomicAdd(hp + 1, acc[ii][1]);
        atomicAdd(hp + 2, acc[ii][2]);
        atomicAdd(hp + 3, acc[ii][3]);
    }
}

// ---------- K6b: geom epilogue + a_s1/a_d1 (512 blocks x 256 thr) ----------
__global__ __launch_bounds__(256) void k_gred(const float* __restrict__ boxesf,
                                              const float* __restrict__ Wg,
                                              const float* __restrict__ asrcf,
                                              const float* __restrict__ adstf,
                                              float* __restrict__ hX,
                                              float* __restrict__ a_s1,
                                              float* __restrict__ a_d1) {
    int i = blockIdx.x, t = threadIdx.x;
    int c = t * 4;
    float4 bx = *(const float4*)(boxesf + i * 4);
    float g0 = bx.x / 800.f, g1 = bx.y / 800.f;
    float g2 = bx.z / 800.f - g0, g3 = bx.w / 800.f - g1;
    float4 v = *(const float4*)(hX + i * 1024 + c);
    float4 w0 = *(const float4*)(Wg + 1024 * 1024 + c);
    float4 w1 = *(const float4*)(Wg + 1025 * 1024 + c);
    float4 w2 = *(const float4*)(Wg + 1026 * 1024 + c);
    float4 w3 = *(const float4*)(Wg + 1027 * 1024 + c);
    v.x += g0 * w0.x + g1 * w1.x + g2 * w2.x + g3 * w3.x;
    v.y += g0 * w0.y + g1 * w1.y + g2 * w2.y + g3 * w3.y;
    v.z += g0 * w0.z + g1 * w1.z + g2 * w2.z + g3 * w3.z;
    v.w += g0 * w0.w + g1 * w1.w + g2 * w2.w + g3 * w3.w;
    *(float4*)(hX + i * 1024 + c) = v;
    float4 as4 = *(const float4*)(asrcf + c);
    float4 ad4 = *(const float4*)(adstf + c);
    float ps = v.x * as4.x + v.y * as4.y + v.z * as4.z + v.w * as4.w;
    float pd = v.x * ad4.x + v.y * ad4.y + v.z * ad4.z + v.w * ad4.w;
    int lane = t & 63, q = t >> 6;   // wave q == head q (cols q*256..q*256+255)
    for (int off = 32; off > 0; off >>= 1) {
        ps += __shfl_down(ps, off);
        pd += __shfl_down(pd, off);
    }
    if (lane == 0) {
        a_s1[i * 4 + q] = ps;
        a_d1[i * 4 + q] = pd;
    }
}

// ---------- K8: GAT1 per-dst softmax + aggregate + bias + relu ----------
__global__ void k_aggr1(const float* __restrict__ hX,
                        const float* __restrict__ a_s, const float* __restrict__ a_d,
                        const int* __restrict__ offs, const int* __restrict__ inlist,
                        const float* __restrict__ bias,
                        float* __restrict__ h1) {
    int n = blockIdx.x, t = threadIdx.x;
    int beg = offs[n], deg = offs[n + 1] - beg;
    if (deg > 513) deg = 513;
    __shared__ int srcs[520];
    __shared__ float alpha[520][4];
    __shared__ float sm[4];
    for (int e = t; e < deg; e += 256) srcs[e] = inlist[beg + e] & 511;
    __syncthreads();
    for (int idx = t; idx < deg * 4; idx += 256) {
        int e = idx >> 2, q = idx & 3;
        float sc = a_s[srcs[e] * 4 + q] + a_d[n * 4 + q];
        alpha[e][q] = (sc >= 0.f) ? sc : 0.2f * sc;
    }
    __syncthreads();
    if (t < 4) {
        float m = -INFINITY;
        for (int e = 0; e < deg; ++e) m = fmaxf(m, alpha[e][t]);
        if (!isfinite(m)) m = 0.f;
        float s = 0.f;
        for (int e = 0; e < deg; ++e) { float ex = expf(alpha[e][t] - m); alpha[e][t] = ex; s += ex; }
        sm[t] = s + 1e-16f;
    }
    __syncthreads();
    for (int idx = t; idx < deg * 4; idx += 256) {
        int e = idx >> 2, q = idx & 3;
        alpha[e][q] /= sm[q];
    }
    __syncthreads();
    for (int q = 0; q < 4; ++q) {
        float acc = 0.f;
        for (int e = 0; e < deg; ++e) acc += alpha[e][q] * hX[srcs[e] * 1024 + q * 256 + t];
        h1[n * 1024 + q * 256 + t] = fmaxf(acc + bias[q * 256 + t], 0.f);
    }
}

// ---------- K9: GAT2 GEMM + a_s2/a_d2 ----------
__global__ __launch_bounds__(256) void k_gat2(const float* __restrict__ h1,
                                              const float* __restrict__ Wf,
                                              const float* __restrict__ asrcf,
                                              const float* __restrict__ adstf,
                                              float* __restrict__ h2,
                                              float* __restrict__ a_s2,
                                              float* __restrict__ a_d2) {
    int n = blockIdx.x, t = threadIdx.x;
    __shared__ float xs[1024];
    __shared__ float hbuf[NCLS];
    __shared__ float sred[256], dred[256];
    for (int c = t; c < 1024; c += 256) xs[c] = h1[n * 1024 + c];
    __syncthreads();
    int cls = t & 127, kh = t >> 7;
    float acc = 0.f;
    if (cls < NCLS) {
        const float* wp = Wf + (kh * 512) * NCLS + cls;
        const float* xp = xs + kh * 512;
        float a0 = 0.f, a1 = 0.f, a2 = 0.f, a3 = 0.f;
        for (int c = 0; c < 512; c += 4) {
            a0 = fmaf(xp[c + 0], wp[(c + 0) * NCLS], a0);
            a1 = fmaf(xp[c + 1], wp[(c + 1) * NCLS], a1);
            a2 = fmaf(xp[c + 2], wp[(c + 2) * NCLS], a2);
            a3 = fmaf(xp[c + 3], wp[(c + 3) * NCLS], a3);
        }
        acc = (a0 + a1) + (a2 + a3);
    }
    if (kh == 0 && cls < NCLS) hbuf[cls] = acc;
    __syncthreads();
    float tot = 0.f;
    int act = (kh == 1 && cls < NCLS);
    if (act) { tot = acc + hbuf[cls]; h2[n * NCLS + cls] = tot; }
    sred[t] = act ? tot * asrcf[cls] : 0.f;
    dred[t] = act ? tot * adstf[cls] : 0.f;
    __syncthreads();
    for (int s = 128; s > 0; s >>= 1) {
        if (t < s) { sred[t] += sred[t + s]; dred[t] += dred[t + s]; }
        __syncthreads();
    }
    if (t == 0) { a_s2[n] = sred[0]; a_d2[n] = dred[0]; }
}

// ---------- K10: GAT2 aggregate -> logits + softmax probs ----------
__global__ void k_aggr2(const float* __restrict__ h2,
                        const float* __restrict__ a_s2, const float* __restrict__ a_d2,
                        const int* __restrict__ offs, const int* __restrict__ inlist,
                        const float* __restrict__ bias,
                        float* __restrict__ logits_out,
                        float* __restrict__ probs_out) {
    int n = blockIdx.x, t = threadIdx.x;
    int beg = offs[n], deg = offs[n + 1] - beg;
    if (deg > 513) deg = 513;
    __shared__ int srcs[520];
    __shared__ float alpha[520];
    __shared__ float red[128];
    __shared__ float smden;
    for (int e = t; e < deg; e += 128) {
        int s = inlist[beg + e] & 511;
        srcs[e] = s;
        float sc = a_s2[s] + a_d2[n];
        alpha[e] = (sc >= 0.f) ? sc : 0.2f * sc;
    }
    __syncthreads();
    if (t == 0) {
        float m = -INFINITY;
        for (int e = 0; e < deg; ++e) m = fmaxf(m, alpha[e]);
        if (!isfinite(m)) m = 0.f;
        float s = 0.f;
        for (int e = 0; e < deg; ++e) { float ex = expf(alpha[e] - m); alpha[e] = ex; s += ex; }
        smden = s + 1e-16f;
    }
    __syncthreads();
    float logit = 0.f;
    if (t < NCLS) {
        float acc = 0.f;
        for (int e = 0; e < deg; ++e) acc += alpha[e] * h2[srcs[e] * NCLS + t];
        logit = acc / smden + bias[t];
        logits_out[n * NCLS + t] = logit;
    }
    red[t] = (t < NCLS) ? logit : -INFINITY; __syncthreads();
    for (int s = 64; s > 0; s >>= 1) { if (t < s) red[t] = fmaxf(red[t], red[t + s]); __syncthreads(); }
    float mx = red[0];
    __syncthreads();
    float ex = (t < NCLS) ? expf(logit - mx) : 0.f;
    red[t] = ex; __syncthreads();
    for (int s = 64; s > 0; s >>= 1) { if (t < s) red[t] += red[t + s]; __syncthreads(); }
    float inv = 1.f / red[0];
    if (t < NCLS) probs_out[n * NCLS + t] = ex * inv;
}

// ---------- launch ----------
extern "C" void kernel_launch(void* const* d_in, const int* in_sizes, int n_in,
                              void* d_out, int out_size, void* d_ws, size_t ws_size,
                              hipStream_t stream) {
    const float* feats   = (const float*)d_in[0];
    const float* boxes   = (const float*)d_in[1];
    const float* repn_w1 = (const float*)d_in[2];
    const float* repn_b1 = (const float*)d_in[3];
    const float* repn_w2 = (const float*)d_in[4];
    const float* repn_b2 = (const float*)d_in[5];
    const float* gat1_w    = (const float*)d_in[6];
    const float* gat1_asrc = (const float*)d_in[7];
    const float* gat1_adst = (const float*)d_in[8];
    const float* gat1_b    = (const float*)d_in[9];
    const float* gat2_w    = (const float*)d_in[10];
    const float* gat2_asrc = (const float*)d_in[11];
    const float* gat2_adst = (const float*)d_in[12];
    const float* gat2_b    = (const float*)d_in[13];
    const int* kp = (const int*)d_in[14];

    float* out = (float*)d_out;
    float* logits_out = out;
    float* probs_out  = out + 512 * NCLS;
    float* rel_out    = out + 2 * 512 * NCLS;

    // Workspace (floats). Liveness:
    //   pp[4] @ [524288,1572864)  live k_p12 -> k_rel
    //   h1    @ [524288,1048576)  live k_aggr1 -> k_gat2      (pp dead)
    //   h2    @ [1048576,1095168) live k_gat2 -> k_aggr2      (pp dead)
    //   a_s1.. + ints @ [1095680,1110540) written AFTER k_rel (pp dead)
    float* wsf  = (float*)d_ws;
    float* hX   = wsf;                 // [0, 524288), zeroed, atomic-accumulated
    float* pp   = wsf + 524288;        // 4 x 262144 partials
    float* h1   = wsf + 524288;
    float* h2   = wsf + 1048576;       // 46592, pad to 1095680
    float* a_s1 = wsf + 1095680;       // 2048
    float* a_d1 = wsf + 1097728;       // 2048
    float* a_s2 = wsf + 1099776;       // 512
    float* a_d2 = wsf + 1100288;       // 512
    int* ib     = (int*)(wsf + 1100800);
    int* count  = ib;                  // 512 (zeroed after k_rel)
    int* cursor = ib + 512;            // 512 (zeroed after k_rel)
    int* nbrs   = ib + 1024;           // 4096
    int* offs   = ib + 5120;           // 520
    int* inlist = ib + 5644;           // 4096

    hipMemsetAsync(hX, 0, 524288 * sizeof(float), stream);

    k_p12<<<dim3(8, 16, 4), dim3(128), 0, stream>>>(feats, repn_w1, pp);
    k_rel<<<dim3(8, 32), dim3(256), 0, stream>>>(pp, repn_w1, repn_b1, repn_w2,
                                                 repn_b2, boxes, rel_out);
    // count+cursor zero AFTER k_rel (their region overlaps pp's range)
    hipMemsetAsync(count, 0, 1024 * sizeof(int), stream);
    k_topk<<<dim3(512), dim3(64), 0, stream>>>(rel_out, kp, nbrs, count);
    k_scan<<<dim3(1), dim3(512), 0, stream>>>(count, offs);
    k_fill<<<dim3(2), dim3(256), 0, stream>>>(nbrs, kp, offs, cursor, inlist);
    k_gat1<<<dim3(16, 16, 4), dim3(128), 0, stream>>>(feats, gat1_w, hX);
    k_gred<<<dim3(512), dim3(256), 0, stream>>>(boxes, gat1_w, gat1_asrc, gat1_adst,
                                                hX, a_s1, a_d1);
    k_aggr1<<<dim3(512), dim3(256), 0, stream>>>(hX, a_s1, a_d1, offs, inlist, gat1_b, h1);
    k_gat2<<<dim3(512), dim3(256), 0, stream>>>(h1, gat2_w, gat2_asrc, gat2_adst,
                                                h2, a_s2, a_d2);
    k_aggr2<<<dim3(512), dim3(128), 0, stream>>>(h2, a_s2, a_d2, offs, inlist, gat2_b,
                                                 logits_out, probs_out);
}